// Round 4
// baseline (894.509 us; speedup 1.0000x reference)
//
#include <hip/hip_runtime.h>
#include <stdint.h>

#define SEQ 16384
#define HIDN 1280
#define NHEADS 16
#define HD 80
#define HDP 96
#define NWIN 16
#define WINSZ 1024

typedef unsigned short u16;
typedef unsigned int u32;
typedef __bf16 bf16x8 __attribute__((ext_vector_type(8)));
typedef float f32x4 __attribute__((ext_vector_type(4)));

#define AS1 __attribute__((address_space(1)))
#define AS3 __attribute__((address_space(3)))

// native cast -> v_cvt_pk_bf16_f32 (RNE)
__device__ __forceinline__ u16 f2b(float f) {
  __bf16 h = (__bf16)f;
  return __builtin_bit_cast(u16, h);
}
__device__ __forceinline__ u32 f2b2(float lo, float hi) {
  __bf16 l = (__bf16)lo, h = (__bf16)hi;
  return (u32)__builtin_bit_cast(u16, l) | ((u32)__builtin_bit_cast(u16, h) << 16);
}
__device__ __forceinline__ float b2f(u16 u) { return __uint_as_float(((u32)u) << 16); }

__device__ __forceinline__ float fexp2(float x) {
#if __has_builtin(__builtin_amdgcn_exp2f)
  return __builtin_amdgcn_exp2f(x);
#else
  return exp2f(x);
#endif
}

__device__ __forceinline__ void load_lds16(const void* g, void* l) {
  __builtin_amdgcn_global_load_lds((AS1 void*)g, (AS3 void*)l, 16, 0, 0);
}

// ---------------- fp32 -> bf16 flat convert ----------------
__global__ void k_cvt(const float* __restrict__ in, u16* __restrict__ out) {
  size_t i = ((size_t)blockIdx.x * 256 + threadIdx.x) * 4;
  float4 v = *(const float4*)(in + i);
  uint2 o;
  o.x = f2b2(v.x, v.y);
  o.y = f2b2(v.z, v.w);
  *(uint2*)(out + i) = o;
}

// ---------------- transpose f32 [R][C] -> bf16 [C][R] ----------------
__global__ void k_trans(const float* __restrict__ in, u16* __restrict__ out, int R, int C) {
  __shared__ float tile[64][65];
  int c0 = blockIdx.x * 64, r0 = blockIdx.y * 64;
  int tc = threadIdx.x & 63, tr4 = threadIdx.x >> 6;
#pragma unroll
  for (int i = 0; i < 16; i++) {
    int r = tr4 + i * 4;
    tile[r][tc] = in[(size_t)(r0 + r) * C + c0 + tc];
  }
  __syncthreads();
#pragma unroll
  for (int i = 0; i < 16; i++) {
    int r = tr4 + i * 4;
    out[(size_t)(c0 + r) * R + r0 + tc] = f2b(tile[tc][r]);
  }
}

// ---------------- 8-phase GEMM: C[M,N] = A[M,K](bf16) * B^T[N,K](bf16) + bias ----------------
// 256x256 tile, 512 thr = 8 waves (2M x 4N), per-wave C = 128x64 = acc[8][4].
// BK=64 in 2 k-halves; LDS 128KB = 2 buf x (A 32K | B 32K), XOR swizzle
// W ^= ((line&7)<<4) (0 bank conflicts, measured R3). 4 phases/tile, 2 barriers
// each; counted vmcnt(4) once per tile. NEW (R4): register-level frag prefetch —
// phase p+1's ds_reads are ISSUED before phase p's MFMA, so compiler-emitted
// counted lgkmcnt lets LDS reads complete under the previous MFMA cluster
// (removes the lockstep read->MFMA serialization that capped MfmaUtil at 34%).
// MODE 0: proj -> f32 out.  MODE 1: qkv -> scatter Q/K [H][S][96], V -> Vt [H][80][S]

#define GBAR() asm volatile("s_barrier" ::: "memory")

template <int MODE>
__launch_bounds__(512, 2)
__global__ void k_gemm8(const u16* __restrict__ A, const u16* __restrict__ B,
                        const float* __restrict__ bias, float* __restrict__ outf,
                        u16* __restrict__ Qb, u16* __restrict__ Kb, u16* __restrict__ Vt,
                        int N, int ncol) {
  extern __shared__ char lds[];
  const int K = 1280;
  const int NT = 20;  // K / 64
  const int tid = threadIdx.x;
  const int wv = tid >> 6, lane = tid & 63;
  const int lr = lane & 15, lq = lane >> 4;
  const int wm = wv >> 2, wn = wv & 3;  // wm 0..1, wn 0..3
  const int id = blockIdx.x;
  const int xs = id & 7, rest = id >> 3;
  const int cb = rest % ncol, rs = rest / ncol;
  const int row0 = (rs * 8 + xs) * 256, col0 = cb * 256;

  // --- staging precompute: 2 slices of 1KB per wave per half-tile ---
  const u16* gA[2];
  const u16* gB[2];
  int Pst[2];
#pragma unroll
  for (int ld = 0; ld < 2; ld++) {
    int P = wv * 2048 + ld * 1024 + lane * 16;  // linear LDS byte within 16KB region
    int j = P >> 7;                              // 128B line
    int Wl = (P & 127) ^ ((j & 7) << 4);         // inverse swizzle -> logical
    int r = 2 * j + (Wl >> 6);                   // logical row 0..255
    int c = (Wl & 63) >> 1;                      // logical col 0..31 (elements)
    gA[ld] = A + (size_t)(row0 + r) * K + c;
    gB[ld] = B + (size_t)(col0 + r) * K + c;
    Pst[ld] = P;
  }

  // --- frag read offsets (physical, swizzled) ---
  int offA[2][4], offB[4];
#pragma unroll
  for (int ch = 0; ch < 2; ch++)
#pragma unroll
    for (int a = 0; a < 4; a++) {
      int r = wm * 128 + ch * 64 + a * 16 + lr;
      int j = r >> 1;
      int Wl = ((r & 1) << 6) | (lq << 4);
      offA[ch][a] = j * 128 + (Wl ^ ((j & 7) << 4));
    }
#pragma unroll
  for (int ni = 0; ni < 4; ni++) {
    int r = wn * 64 + ni * 16 + lr;
    int j = r >> 1;
    int Wl = ((r & 1) << 6) | (lq << 4);
    offB[ni] = 32768 + j * 128 + (Wl ^ ((j & 7) << 4));
  }

  f32x4 acc[8][4];
#pragma unroll
  for (int i = 0; i < 8; i++)
#pragma unroll
    for (int j = 0; j < 4; j++) acc[i][j] = (f32x4){0.f, 0.f, 0.f, 0.f};

// stage half-tile (mat: 0=A 1=B, kh, kt) -> LDS buf (kt&1)
#define STAGE(mat_, kh_, kt_)                                        \
  do {                                                               \
    char* lb_ = lds + (((kt_) & 1) << 16) + ((mat_) << 15) + ((kh_) << 14); \
    const u16* g0_ = (mat_) ? gB[0] : gA[0];                         \
    const u16* g1_ = (mat_) ? gB[1] : gA[1];                         \
    int ko_ = (kt_) * 64 + (kh_) * 32;                               \
    load_lds16(g0_ + ko_, lb_ + Pst[0]);                             \
    load_lds16(g1_ + ko_, lb_ + Pst[1]);                             \
  } while (0)

#define MFMA16(dst_, af_, bf_)                                               \
  do {                                                                       \
    __builtin_amdgcn_s_setprio(1);                                           \
    _Pragma("unroll") for (int a_ = 0; a_ < 4; a_++)                         \
        _Pragma("unroll") for (int n_ = 0; n_ < 4; n_++)                     \
            acc[dst_ + a_][n_] = __builtin_amdgcn_mfma_f32_16x16x32_bf16(    \
                af_[a_], bf_[n_], acc[dst_ + a_][n_], 0, 0, 0);              \
    __builtin_amdgcn_s_setprio(0);                                           \
  } while (0)

  // --- prologue: halves = tile0{Ak0,Bk0,Ak1,Bk1}, tile1{Ak0,Bk0} ---
  STAGE(0, 0, 0);
  STAGE(1, 0, 0);
  STAGE(0, 1, 0);
  STAGE(1, 1, 0);
  STAGE(0, 0, 1);
  STAGE(1, 0, 1);
  asm volatile("s_waitcnt vmcnt(4)" ::: "memory");  // tile0 fully landed
  GBAR();

  // frags for upcoming phase 0 (loop-carried)
  bf16x8 b0[4], a0[4];
#pragma unroll
  for (int ni = 0; ni < 4; ni++) b0[ni] = *(const bf16x8*)(lds + offB[ni]);
#pragma unroll
  for (int a = 0; a < 4; a++) a0[a] = *(const bf16x8*)(lds + offA[0][a]);

#pragma unroll 2
  for (int t = 0; t < NT; t++) {
    const int bb = (t & 1) << 16;
    bf16x8 a1[4], b2[4], a2[4], a3[4];

    // ---- phase 0: MFMA(kh0,ch0); prefetch a1(kh0,ch1); stage A-k1 of t+1 ----
    if (t + 1 < NT) STAGE(0, 1, t + 1);
#pragma unroll
    for (int a = 0; a < 4; a++) a1[a] = *(const bf16x8*)(lds + bb + offA[1][a]);
    GBAR();
    MFMA16(0, a0, b0);
    GBAR();

    // ---- phase 1: MFMA(kh0,ch1); prefetch b2,a2 (kh1); stage B-k1 of t+1 ----
    if (t + 1 < NT) STAGE(1, 1, t + 1);
#pragma unroll
    for (int ni = 0; ni < 4; ni++) b2[ni] = *(const bf16x8*)(lds + bb + 16384 + offB[ni]);
#pragma unroll
    for (int a = 0; a < 4; a++) a2[a] = *(const bf16x8*)(lds + bb + 16384 + offA[0][a]);
    GBAR();
    MFMA16(4, a1, b0);
    GBAR();

    // ---- phase 2: MFMA(kh1,ch0); prefetch a3(kh1,ch1); stage A-k0 of t+2 ----
    if (t + 2 < NT) STAGE(0, 0, t + 2);
#pragma unroll
    for (int a = 0; a < 4; a++) a3[a] = *(const bf16x8*)(lds + bb + 16384 + offA[1][a]);
    GBAR();
    MFMA16(0, a2, b2);
    GBAR();

    // ---- phase 3: stage B-k0 of t+2; tile-boundary vmcnt; prefetch next-tile
    //      ph0 frags AFTER the barrier (t+1 buffer landed+visible); MFMA(kh1,ch1) ----
    if (t + 2 < NT) STAGE(1, 0, t + 2);
    if (t < NT - 2)
      asm volatile("s_waitcnt vmcnt(4)" ::: "memory");  // tile t+1 fully landed
    else if (t == NT - 2)
      asm volatile("s_waitcnt vmcnt(0)" ::: "memory");  // tail drain
    GBAR();
    if (t + 1 < NT) {
      const int nb = ((t + 1) & 1) << 16;
#pragma unroll
      for (int ni = 0; ni < 4; ni++) b0[ni] = *(const bf16x8*)(lds + nb + offB[ni]);
#pragma unroll
      for (int a = 0; a < 4; a++) a0[a] = *(const bf16x8*)(lds + nb + offA[0][a]);
    }
    MFMA16(4, a3, b2);
    GBAR();
  }
#undef STAGE
#undef MFMA16

  // --- epilogue: C/D layout col=lane&15, row=(lane>>4)*4+reg ---
#pragma unroll
  for (int ni = 0; ni < 4; ni++) {
    int col = col0 + wn * 64 + ni * 16 + lr;
    float bs = bias[col];
    if (MODE == 0) {
#pragma unroll
      for (int mi = 0; mi < 8; mi++)
#pragma unroll
        for (int r = 0; r < 4; r++) {
          int row = row0 + wm * 128 + mi * 16 + lq * 4 + r;
          outf[(size_t)row * N + col] = acc[mi][ni][r] + bs;
        }
    } else {
      int seg = col / HIDN;  // 0=q 1=k 2=v (uniform per 16-col tile)
      int cl = col - seg * HIDN;
      int h = cl / HD, d = cl - h * HD;
      if (seg == 2) {
#pragma unroll
        for (int mi = 0; mi < 8; mi++) {
          int row = row0 + wm * 128 + mi * 16 + lq * 4;
          uint2 o;
          o.x = f2b2(acc[mi][ni][0] + bs, acc[mi][ni][1] + bs);
          o.y = f2b2(acc[mi][ni][2] + bs, acc[mi][ni][3] + bs);
          *(uint2*)(Vt + ((size_t)h * HD + d) * SEQ + row) = o;
        }
      } else {
        u16* Dst = (seg == 0) ? Qb : Kb;
#pragma unroll
        for (int mi = 0; mi < 8; mi++)
#pragma unroll
          for (int r = 0; r < 4; r++) {
            int row = row0 + wm * 128 + mi * 16 + lq * 4 + r;
            Dst[((size_t)h * SEQ + row) * HDP + d] = f2b(acc[mi][ni][r] + bs);
          }
      }
    }
  }
}

// ---------------- in-place RoPE on Q and K [H][S][96] bf16, zero pad ----------------
__global__ void k_rope2(u16* __restrict__ Q, u16* __restrict__ K,
                        const float* __restrict__ cs, const float* __restrict__ sn) {
  int idx = blockIdx.x * 256 + threadIdx.x;  // [0, 2*16*16384*10)
  const int TOT = NHEADS * SEQ * 10;
  u16* X = Q;
  if (idx >= TOT) { X = K; idx -= TOT; }
  int h = idx / (SEQ * 10);
  int rem = idx - h * (SEQ * 10);
  int s = rem / 10;
  int t = rem - s * 10;
  int d = t * 4;
  size_t base = ((size_t)h * SEQ + s) * HDP;
  float4 cv = *(const float4*)(cs + s * HD + d);
  float4 sv = *(const float4*)(sn + s * HD + d);
  uint2 a = *(const uint2*)(X + base + d);
  uint2 b = *(const uint2*)(X + base + d + 40);
  float x1[4], x2[4];
  x1[0] = b2f(a.x & 0xffffu); x1[1] = b2f(a.x >> 16);
  x1[2] = b2f(a.y & 0xffffu); x1[3] = b2f(a.y >> 16);
  x2[0] = b2f(b.x & 0xffffu); x2[1] = b2f(b.x >> 16);
  x2[2] = b2f(b.y & 0xffffu); x2[3] = b2f(b.y >> 16);
  uint2 o1, o2;
  o1.x = f2b2(x1[0] * cv.x - x2[0] * sv.x, x1[1] * cv.y - x2[1] * sv.y);
  o1.y = f2b2(x1[2] * cv.z - x2[2] * sv.z, x1[3] * cv.w - x2[3] * sv.w);
  o2.x = f2b2(x2[0] * cv.x + x1[0] * sv.x, x2[1] * cv.y + x1[1] * sv.y);
  o2.y = f2b2(x2[2] * cv.z + x1[2] * sv.z, x2[3] * cv.w + x1[3] * sv.w);
  *(uint2*)(X + base + d) = o1;
  *(uint2*)(X + base + d + 40) = o2;
  if (t < 4) {
    uint2 z; z.x = 0; z.y = 0;
    *(uint2*)(X + base + 80 + t * 4) = z;
  }
}

// ---------------- windowed flash attention ----------------
__launch_bounds__(256, 2)
__global__ void k_attn(const u16* __restrict__ Qb, const u16* __restrict__ Kb,
                       const u16* __restrict__ Vt, u16* __restrict__ Ob) {
  __shared__ char lds[24576 + 20480 + 4 * 4352];
  char* ldsK = lds;
  char* ldsV = lds + 24576;
  char* ldsP = lds + 45056;

  const int tid = threadIdx.x;
  const int wv = tid >> 6, lane = tid & 63;
  const int lr = lane & 15, lq = lane >> 4;

  const int b = blockIdx.x;
  const int qblk = b & 7, h = (b >> 3) & 15, w = b >> 7;
  const int q0 = w * WINSZ + qblk * 128 + wv * 32;
  const int kwin = w * WINSZ;

  bf16x8 qf[2][3];
#pragma unroll
  for (int qt = 0; qt < 2; qt++)
#pragma unroll
    for (int ds = 0; ds < 3; ds++)
      qf[qt][ds] = *(const bf16x8*)(Qb + ((size_t)h * SEQ + q0 + qt * 16 + lr) * HDP + ds * 32 + lq * 8);

  f32x4 acc[2][5];
#pragma unroll
  for (int i = 0; i < 2; i++)
#pragma unroll
    for (int j = 0; j < 5; j++) acc[i][j] = (f32x4){0.f, 0.f, 0.f, 0.f};
  float mo[2] = {-1e30f, -1e30f};
  float lsum[2] = {0.f, 0.f};
  const float kscale = 0.11180339887498949f * 1.4426950408889634f;  // 1/sqrt(80) * log2(e)

  for (int kt = 0; kt < 8; kt++) {
    int k0 = kwin + kt * 128;
#pragma unroll
    for (int li = 0; li < 11; li++) {
      int g = li * 4 + wv;
      const u16* gp;
      char* lp;
      if (g < 24) {
        int kt16 = g / 3, ds = g - kt16 * 3;
        gp = Kb + ((size_t)h * SEQ + k0 + kt16 * 16 + lr) * HDP + ds * 32 + lq * 8;
        lp = ldsK + g * 1024;
      } else {
        int g2 = g - 24;
        int dt = g2 >> 2, ks = g2 & 3;
        gp = Vt + ((size_t)h * HD + dt * 16 + lr) * SEQ + k0 + ks * 32 + lq * 8;
        lp = ldsV + g2 * 1024;
      }
      load_lds16(gp, lp);
    }
    __syncthreads();

    f32x4 sx[2][8];
#pragma unroll
    for (int i = 0; i < 2; i++)
#pragma unroll
      for (int j = 0; j < 8; j++) sx[i][j] = (f32x4){0.f, 0.f, 0.f, 0.f};
    __builtin_amdgcn_s_setprio(1);
#pragma unroll
    for (int kt16 = 0; kt16 < 8; kt16++) {
      bf16x8 kf0 = *(const bf16x8*)(ldsK + (kt16 * 3 + 0) * 1024 + lane * 16);
      bf16x8 kf1 = *(const bf16x8*)(ldsK + (kt16 * 3 + 1) * 1024 + lane * 16);
      bf16x8 kf2 = *(const bf16x8*)(ldsK + (kt16 * 3 + 2) * 1024 + lane * 16);
#pragma unroll
      for (int qt = 0; qt < 2; qt++) {
        sx[qt][kt16] = __builtin_amdgcn_mfma_f32_16x16x32_bf16(kf0, qf[qt][0], sx[qt][kt16], 0, 0, 0);
        sx[qt][kt16] = __builtin_amdgcn_mfma_f32_16x16x32_bf16(kf1, qf[qt][1], sx[qt][kt16], 0, 0, 0);
        sx[qt][kt16] = __builtin_amdgcn_mfma_f32_16x16x32_bf16(kf2, qf[qt][2], sx[qt][kt16], 0, 0, 0);
      }
    }
    __builtin_amdgcn_s_setprio(0);

    bf16x8 pf[2][4];
#pragma unroll
    for (int qt = 0; qt < 2; qt++) {
      float mx = -1e30f;
#pragma unroll
      for (int t = 0; t < 8; t++)
#pragma unroll
        for (int r = 0; r < 4; r++) mx = fmaxf(mx, sx[qt][t][r]);
      mx = fmaxf(mx, __shfl_xor(mx, 16));
      mx = fmaxf(mx, __shfl_xor(mx, 32));
      float mxs = mx * kscale;
      if (!__all(mxs <= mo[qt] + 8.f)) {
        float mnew = fmaxf(mo[qt], mxs);
        float alpha = fexp2(mo[qt] - mnew);
        mo[qt] = mnew;
        lsum[qt] *= alpha;
#pragma unroll
        for (int dt = 0; dt < 5; dt++) acc[qt][dt] *= alpha;
      }
      float ls = 0.f;
#pragma unroll
      for (int t = 0; t < 8; t++)
#pragma unroll
        for (int r = 0; r < 4; r++) {
          float p = fexp2(fmaf(sx[qt][t][r], kscale, -mo[qt]));
          sx[qt][t][r] = p;
          ls += p;
        }
      ls += __shfl_xor(ls, 16);
      ls += __shfl_xor(ls, 32);
      lsum[qt] += ls;
      char* pw = ldsP + wv * 4352;
#pragma unroll
      for (int t = 0; t < 8; t++) {
        uint2 o;
        o.x = f2b2(sx[qt][t][0], sx[qt][t][1]);
        o.y = f2b2(sx[qt][t][2], sx[qt][t][3]);
        *(uint2*)(pw + lr * 272 + t * 32 + lq * 8) = o;
      }
#pragma unroll
      for (int ks = 0; ks < 4; ks++)
        pf[qt][ks] = *(const bf16x8*)(pw + lr * 272 + ks * 64 + lq * 16);
    }

    __builtin_amdgcn_s_setprio(1);
#pragma unroll
    for (int dt = 0; dt < 5; dt++)
#pragma unroll
      for (int ks = 0; ks < 4; ks++) {
        bf16x8 vf = *(const bf16x8*)(ldsV + (dt * 4 + ks) * 1024 + lane * 16);
#pragma unroll
        for (int qt = 0; qt < 2; qt++)
          acc[qt][dt] = __builtin_amdgcn_mfma_f32_16x16x32_bf16(vf, pf[qt][ks], acc[qt][dt], 0, 0, 0);
      }
    __builtin_amdgcn_s_setprio(0);
    __syncthreads();
  }

#pragma unroll
  for (int qt = 0; qt < 2; qt++) {
    float rl = 1.f / lsum[qt];
    int s = q0 + qt * 16 + lr;
#pragma unroll
    for (int dt = 0; dt < 5; dt++) {
      uint2 o;
      o.x = f2b2(acc[qt][dt][0] * rl, acc[qt][dt][1] * rl);
      o.y = f2b2(acc[qt][dt][2] * rl, acc[qt][dt][3] * rl);
      size_t ob = (size_t)s * HIDN + h * HD + dt * 16 + lq * 4;
      *(uint2*)(Ob + ob) = o;
    }
  }
}

// ---------------- launch ----------------
extern "C" void kernel_launch(void* const* d_in, const int* in_sizes, int n_in,
                              void* d_out, int out_size, void* d_ws, size_t ws_size,
                              hipStream_t stream) {
  (void)in_sizes; (void)n_in; (void)out_size; (void)ws_size;
  const float* hidden = (const float*)d_in[0];
  const float* cosb   = (const float*)d_in[1];
  const float* sinb   = (const float*)d_in[2];
  const float* qkvk   = (const float*)d_in[3];
  const float* qkvb   = (const float*)d_in[4];
  const float* projk  = (const float*)d_in[5];
  const float* projb  = (const float*)d_in[6];
  // d_in[7] cu_seqlens: uniform windows, unused

  char* ws = (char*)d_ws;
  u16* Abf = (u16*)(ws + 0);          // 41,943,040 B ; reused as attn-out after gemm1
  u16* Wt  = (u16*)(ws + 41943040);   //  9,830,400 B
  u16* Pt  = (u16*)(ws + 51773440);   //  3,276,800 B
  u16* Qb  = (u16*)(ws + 55050240);   // 50,331,648 B
  u16* Kb  = (u16*)(ws + 105381888);  // 50,331,648 B
  u16* Vtb = (u16*)(ws + 155713536);  // 41,943,040 B -> total 197,656,576 B

  static int attr_done = 0;
  if (!attr_done) {
    (void)hipFuncSetAttribute((const void*)&k_gemm8<1>,
                              hipFuncAttributeMaxDynamicSharedMemorySize, 131072);
    (void)hipFuncSetAttribute((const void*)&k_gemm8<0>,
                              hipFuncAttributeMaxDynamicSharedMemorySize, 131072);
    (void)hipGetLastError();  // clear any sticky error from attribute calls
    attr_done = 1;
  }

  k_cvt<<<20480, 256, 0, stream>>>(hidden, Abf);
  k_trans<<<dim3(60, 20), 256, 0, stream>>>(qkvk, Wt, 1280, 3840);
  k_trans<<<dim3(20, 20), 256, 0, stream>>>(projk, Pt, 1280, 1280);
  // qkv: M=16384 N=3840 -> 64 x 15 tiles of 256x256 = 960 blocks
  k_gemm8<1><<<960, 512, 131072, stream>>>(Abf, Wt, qkvb, nullptr, Qb, Kb, Vtb, 3840, 15);
  // rope on Q and K, one launch
  k_rope2<<<20480, 256, 0, stream>>>(Qb, Kb, cosb, sinb);
  k_attn<<<2048, 256, 0, stream>>>(Qb, Kb, Vtb, Abf);
  // proj: M=16384 N=1280 -> 64 x 5 tiles of 256x256 = 320 blocks
  k_gemm8<0><<<320, 512, 131072, stream>>>(Abf, Pt, projb, (float*)d_out,
                                           nullptr, nullptr, nullptr, 1280, 5);
}

// Round 5
// 618.909 us; speedup vs baseline: 1.4453x; 1.4453x over previous
//
#include <hip/hip_runtime.h>
#include <stdint.h>

#define SEQ 16384
#define HIDN 1280
#define NHEADS 16
#define HD 80
#define HDP 96
#define NWIN 16
#define WINSZ 1024

typedef unsigned short u16;
typedef unsigned int u32;
typedef __bf16 bf16x8 __attribute__((ext_vector_type(8)));
typedef float f32x4 __attribute__((ext_vector_type(4)));

#define AS1 __attribute__((address_space(1)))
#define AS3 __attribute__((address_space(3)))

// native cast -> v_cvt_pk_bf16_f32 (RNE)
__device__ __forceinline__ u16 f2b(float f) {
  __bf16 h = (__bf16)f;
  return __builtin_bit_cast(u16, h);
}
__device__ __forceinline__ u32 f2b2(float lo, float hi) {
  __bf16 l = (__bf16)lo, h = (__bf16)hi;
  return (u32)__builtin_bit_cast(u16, l) | ((u32)__builtin_bit_cast(u16, h) << 16);
}
__device__ __forceinline__ float b2f(u16 u) { return __uint_as_float(((u32)u) << 16); }

__device__ __forceinline__ float fexp2(float x) {
#if __has_builtin(__builtin_amdgcn_exp2f)
  return __builtin_amdgcn_exp2f(x);
#else
  return exp2f(x);
#endif
}

__device__ __forceinline__ void load_lds16(const void* g, void* l) {
  __builtin_amdgcn_global_load_lds((AS1 void*)g, (AS3 void*)l, 16, 0, 0);
}

// ---------------- fp32 -> bf16 flat convert ----------------
__global__ void k_cvt(const float* __restrict__ in, u16* __restrict__ out) {
  size_t i = ((size_t)blockIdx.x * 256 + threadIdx.x) * 4;
  float4 v = *(const float4*)(in + i);
  uint2 o;
  o.x = f2b2(v.x, v.y);
  o.y = f2b2(v.z, v.w);
  *(uint2*)(out + i) = o;
}

// ---------------- transpose f32 [R][C] -> bf16 [C][R] ----------------
__global__ void k_trans(const float* __restrict__ in, u16* __restrict__ out, int R, int C) {
  __shared__ float tile[64][65];
  int c0 = blockIdx.x * 64, r0 = blockIdx.y * 64;
  int tc = threadIdx.x & 63, tr4 = threadIdx.x >> 6;
#pragma unroll
  for (int i = 0; i < 16; i++) {
    int r = tr4 + i * 4;
    tile[r][tc] = in[(size_t)(r0 + r) * C + c0 + tc];
  }
  __syncthreads();
#pragma unroll
  for (int i = 0; i < 16; i++) {
    int r = tr4 + i * 4;
    out[(size_t)(c0 + r) * R + r0 + tc] = f2b(tile[tc][r]);
  }
}

// ---------------- deep-pipe GEMM: C[M,N] = A[M,K](bf16) * B^T[N,K](bf16) + bias ----------------
// 256x256 tile, 512 thr = 8 waves (2M x 4N), per-wave C = 128x64 = acc[8][4] (AGPR).
// BK=32, FOUR LDS buffers (4 x 32KB = 128KB), stage tile t+3 during tile t:
// vmcnt(8) at tile end waits on loads issued 4-5 phases (~1000+ cyc) earlier,
// covering HBM latency (R3's 2-buf schedule waited on ~400-cyc-old loads ->
// ~500 cyc stall/tile -> MfmaUtil 34%). XOR swizzle W ^= ((line&7)<<4)
// (0 bank conflicts, measured). 2 phases/tile (M-halves), 16 MFMA each,
// 2 barriers/phase. No register frag prefetch (R4 lesson: unified VGPR+AGPR
// file is at ~252/256 -> any extra live frags spill to scratch).
// MODE 0: proj -> f32 out.  MODE 1: qkv -> scatter Q/K [H][S][96], V -> Vt [H][80][S]

#define GBAR() asm volatile("s_barrier" ::: "memory")

template <int MODE>
__launch_bounds__(512, 2)
__global__ void k_gemm8(const u16* __restrict__ A, const u16* __restrict__ B,
                        const float* __restrict__ bias, float* __restrict__ outf,
                        u16* __restrict__ Qb, u16* __restrict__ Kb, u16* __restrict__ Vt,
                        int N, int ncol) {
  extern __shared__ char lds[];
  const int K = 1280;
  const int NT = 40;  // K / 32
  const int tid = threadIdx.x;
  const int wv = tid >> 6, lane = tid & 63;
  const int lr = lane & 15, lq = lane >> 4;
  const int wm = wv >> 2, wn = wv & 3;  // wm 0..1, wn 0..3
  const int id = blockIdx.x;
  const int xs = id & 7, rest = id >> 3;
  const int cb = rest % ncol, rs = rest / ncol;
  const int row0 = (rs * 8 + xs) * 256, col0 = cb * 256;

  // --- staging precompute: 2 slices of 1KB per wave per matrix per tile ---
  // region = 16KB: 256 logical rows x 32 cols (64B/row), line=128B=2 rows,
  // physical W = logical ^ ((line&7)<<4); global src pre-inverse-swizzled.
  const u16* gA[2];
  const u16* gB[2];
  int Pst[2];
#pragma unroll
  for (int ld = 0; ld < 2; ld++) {
    int P = wv * 2048 + ld * 1024 + lane * 16;  // linear LDS byte within 16KB region
    int j = P >> 7;                              // 128B line
    int Wl = (P & 127) ^ ((j & 7) << 4);         // inverse swizzle -> logical
    int r = 2 * j + (Wl >> 6);                   // logical row 0..255
    int c = (Wl & 63) >> 1;                      // logical col 0..31 (elements)
    gA[ld] = A + (size_t)(row0 + r) * K + c;
    gB[ld] = B + (size_t)(col0 + r) * K + c;
    Pst[ld] = P;
  }

  // --- frag read offsets (physical, swizzled) ---
  int offA[2][4], offB[4];
#pragma unroll
  for (int ch = 0; ch < 2; ch++)
#pragma unroll
    for (int a = 0; a < 4; a++) {
      int r = wm * 128 + ch * 64 + a * 16 + lr;
      int j = r >> 1;
      int Wl = ((r & 1) << 6) | (lq << 4);
      offA[ch][a] = j * 128 + (Wl ^ ((j & 7) << 4));
    }
#pragma unroll
  for (int ni = 0; ni < 4; ni++) {
    int r = wn * 64 + ni * 16 + lr;
    int j = r >> 1;
    int Wl = ((r & 1) << 6) | (lq << 4);
    offB[ni] = 16384 + j * 128 + (Wl ^ ((j & 7) << 4));
  }

  f32x4 acc[8][4];
#pragma unroll
  for (int i = 0; i < 8; i++)
#pragma unroll
    for (int j = 0; j < 4; j++) acc[i][j] = (f32x4){0.f, 0.f, 0.f, 0.f};

// stage one matrix tile (mat: 0=A 1=B) of K-tile kt -> LDS buf (kt&3)
#define STAGE(mat_, kt_)                                             \
  do {                                                               \
    char* lb_ = lds + (((kt_) & 3) << 15) + ((mat_) << 14);          \
    const u16* g0_ = (mat_) ? gB[0] : gA[0];                         \
    const u16* g1_ = (mat_) ? gB[1] : gA[1];                         \
    int ko_ = (kt_) * 32;                                            \
    load_lds16(g0_ + ko_, lb_ + Pst[0]);                             \
    load_lds16(g1_ + ko_, lb_ + Pst[1]);                             \
  } while (0)

#define MFMA16(dst_, af_, bf_)                                               \
  do {                                                                       \
    __builtin_amdgcn_s_setprio(1);                                           \
    _Pragma("unroll") for (int a_ = 0; a_ < 4; a_++)                         \
        _Pragma("unroll") for (int n_ = 0; n_ < 4; n_++)                     \
            acc[dst_ + a_][n_] = __builtin_amdgcn_mfma_f32_16x16x32_bf16(    \
                af_[a_], bf_[n_], acc[dst_ + a_][n_], 0, 0, 0);              \
    __builtin_amdgcn_s_setprio(0);                                           \
  } while (0)

  // --- prologue: stage tiles 0,1,2 (12 loads/thread) ---
  STAGE(0, 0);
  STAGE(1, 0);
  STAGE(0, 1);
  STAGE(1, 1);
  STAGE(0, 2);
  STAGE(1, 2);
  asm volatile("s_waitcnt vmcnt(8)" ::: "memory");  // tile0 fully landed
  GBAR();

#pragma unroll 4
  for (int t = 0; t < NT; t++) {
    const int bb = (t & 3) << 15;
    bf16x8 bfr[4], af0[4], af1[4];

    // ---- phase 0 (M-half 0): read B + A0 frags; stage A of t+3 ----
#pragma unroll
    for (int ni = 0; ni < 4; ni++) bfr[ni] = *(const bf16x8*)(lds + bb + offB[ni]);
#pragma unroll
    for (int a = 0; a < 4; a++) af0[a] = *(const bf16x8*)(lds + bb + offA[0][a]);
    if (t + 3 < NT) STAGE(0, t + 3);
    GBAR();
    MFMA16(0, af0, bfr);
    GBAR();

    // ---- phase 1 (M-half 1): read A1 frags; stage B of t+3; tile-boundary vmcnt ----
#pragma unroll
    for (int a = 0; a < 4; a++) af1[a] = *(const bf16x8*)(lds + bb + offA[1][a]);
    if (t + 3 < NT) STAGE(1, t + 3);
    if (t + 3 < NT)
      asm volatile("s_waitcnt vmcnt(8)" ::: "memory");  // tile t+1 fully landed
    else if (t == NT - 3)
      asm volatile("s_waitcnt vmcnt(4)" ::: "memory");
    else if (t == NT - 2)
      asm volatile("s_waitcnt vmcnt(0)" ::: "memory");
    GBAR();
    MFMA16(4, af1, bfr);
    GBAR();
  }
#undef STAGE
#undef MFMA16

  // --- epilogue: C/D layout col=lane&15, row=(lane>>4)*4+reg ---
#pragma unroll
  for (int ni = 0; ni < 4; ni++) {
    int col = col0 + wn * 64 + ni * 16 + lr;
    float bs = bias[col];
    if (MODE == 0) {
#pragma unroll
      for (int mi = 0; mi < 8; mi++)
#pragma unroll
        for (int r = 0; r < 4; r++) {
          int row = row0 + wm * 128 + mi * 16 + lq * 4 + r;
          outf[(size_t)row * N + col] = acc[mi][ni][r] + bs;
        }
    } else {
      int seg = col / HIDN;  // 0=q 1=k 2=v (uniform per 16-col tile)
      int cl = col - seg * HIDN;
      int h = cl / HD, d = cl - h * HD;
      if (seg == 2) {
#pragma unroll
        for (int mi = 0; mi < 8; mi++) {
          int row = row0 + wm * 128 + mi * 16 + lq * 4;
          uint2 o;
          o.x = f2b2(acc[mi][ni][0] + bs, acc[mi][ni][1] + bs);
          o.y = f2b2(acc[mi][ni][2] + bs, acc[mi][ni][3] + bs);
          *(uint2*)(Vt + ((size_t)h * HD + d) * SEQ + row) = o;
        }
      } else {
        u16* Dst = (seg == 0) ? Qb : Kb;
#pragma unroll
        for (int mi = 0; mi < 8; mi++)
#pragma unroll
          for (int r = 0; r < 4; r++) {
            int row = row0 + wm * 128 + mi * 16 + lq * 4 + r;
            Dst[((size_t)h * SEQ + row) * HDP + d] = f2b(acc[mi][ni][r] + bs);
          }
      }
    }
  }
}

// ---------------- in-place RoPE on Q and K [H][S][96] bf16, zero pad ----------------
__global__ void k_rope2(u16* __restrict__ Q, u16* __restrict__ K,
                        const float* __restrict__ cs, const float* __restrict__ sn) {
  int idx = blockIdx.x * 256 + threadIdx.x;  // [0, 2*16*16384*10)
  const int TOT = NHEADS * SEQ * 10;
  u16* X = Q;
  if (idx >= TOT) { X = K; idx -= TOT; }
  int h = idx / (SEQ * 10);
  int rem = idx - h * (SEQ * 10);
  int s = rem / 10;
  int t = rem - s * 10;
  int d = t * 4;
  size_t base = ((size_t)h * SEQ + s) * HDP;
  float4 cv = *(const float4*)(cs + s * HD + d);
  float4 sv = *(const float4*)(sn + s * HD + d);
  uint2 a = *(const uint2*)(X + base + d);
  uint2 b = *(const uint2*)(X + base + d + 40);
  float x1[4], x2[4];
  x1[0] = b2f(a.x & 0xffffu); x1[1] = b2f(a.x >> 16);
  x1[2] = b2f(a.y & 0xffffu); x1[3] = b2f(a.y >> 16);
  x2[0] = b2f(b.x & 0xffffu); x2[1] = b2f(b.x >> 16);
  x2[2] = b2f(b.y & 0xffffu); x2[3] = b2f(b.y >> 16);
  uint2 o1, o2;
  o1.x = f2b2(x1[0] * cv.x - x2[0] * sv.x, x1[1] * cv.y - x2[1] * sv.y);
  o1.y = f2b2(x1[2] * cv.z - x2[2] * sv.z, x1[3] * cv.w - x2[3] * sv.w);
  o2.x = f2b2(x2[0] * cv.x + x1[0] * sv.x, x2[1] * cv.y + x1[1] * sv.y);
  o2.y = f2b2(x2[2] * cv.z + x1[2] * sv.z, x2[3] * cv.w + x1[3] * sv.w);
  *(uint2*)(X + base + d) = o1;
  *(uint2*)(X + base + d + 40) = o2;
  if (t < 4) {
    uint2 z; z.x = 0; z.y = 0;
    *(uint2*)(X + base + 80 + t * 4) = z;
  }
}

// ---------------- windowed flash attention ----------------
__launch_bounds__(256, 2)
__global__ void k_attn(const u16* __restrict__ Qb, const u16* __restrict__ Kb,
                       const u16* __restrict__ Vt, u16* __restrict__ Ob) {
  __shared__ char lds[24576 + 20480 + 4 * 4352];
  char* ldsK = lds;
  char* ldsV = lds + 24576;
  char* ldsP = lds + 45056;

  const int tid = threadIdx.x;
  const int wv = tid >> 6, lane = tid & 63;
  const int lr = lane & 15, lq = lane >> 4;

  const int b = blockIdx.x;
  const int qblk = b & 7, h = (b >> 3) & 15, w = b >> 7;
  const int q0 = w * WINSZ + qblk * 128 + wv * 32;
  const int kwin = w * WINSZ;

  bf16x8 qf[2][3];
#pragma unroll
  for (int qt = 0; qt < 2; qt++)
#pragma unroll
    for (int ds = 0; ds < 3; ds++)
      qf[qt][ds] = *(const bf16x8*)(Qb + ((size_t)h * SEQ + q0 + qt * 16 + lr) * HDP + ds * 32 + lq * 8);

  f32x4 acc[2][5];
#pragma unroll
  for (int i = 0; i < 2; i++)
#pragma unroll
    for (int j = 0; j < 5; j++) acc[i][j] = (f32x4){0.f, 0.f, 0.f, 0.f};
  float mo[2] = {-1e30f, -1e30f};
  float lsum[2] = {0.f, 0.f};
  const float kscale = 0.11180339887498949f * 1.4426950408889634f;  // 1/sqrt(80) * log2(e)

  for (int kt = 0; kt < 8; kt++) {
    int k0 = kwin + kt * 128;
#pragma unroll
    for (int li = 0; li < 11; li++) {
      int g = li * 4 + wv;
      const u16* gp;
      char* lp;
      if (g < 24) {
        int kt16 = g / 3, ds = g - kt16 * 3;
        gp = Kb + ((size_t)h * SEQ + k0 + kt16 * 16 + lr) * HDP + ds * 32 + lq * 8;
        lp = ldsK + g * 1024;
      } else {
        int g2 = g - 24;
        int dt = g2 >> 2, ks = g2 & 3;
        gp = Vt + ((size_t)h * HD + dt * 16 + lr) * SEQ + k0 + ks * 32 + lq * 8;
        lp = ldsV + g2 * 1024;
      }
      load_lds16(gp, lp);
    }
    __syncthreads();

    f32x4 sx[2][8];
#pragma unroll
    for (int i = 0; i < 2; i++)
#pragma unroll
      for (int j = 0; j < 8; j++) sx[i][j] = (f32x4){0.f, 0.f, 0.f, 0.f};
    __builtin_amdgcn_s_setprio(1);
#pragma unroll
    for (int kt16 = 0; kt16 < 8; kt16++) {
      bf16x8 kf0 = *(const bf16x8*)(ldsK + (kt16 * 3 + 0) * 1024 + lane * 16);
      bf16x8 kf1 = *(const bf16x8*)(ldsK + (kt16 * 3 + 1) * 1024 + lane * 16);
      bf16x8 kf2 = *(const bf16x8*)(ldsK + (kt16 * 3 + 2) * 1024 + lane * 16);
#pragma unroll
      for (int qt = 0; qt < 2; qt++) {
        sx[qt][kt16] = __builtin_amdgcn_mfma_f32_16x16x32_bf16(kf0, qf[qt][0], sx[qt][kt16], 0, 0, 0);
        sx[qt][kt16] = __builtin_amdgcn_mfma_f32_16x16x32_bf16(kf1, qf[qt][1], sx[qt][kt16], 0, 0, 0);
        sx[qt][kt16] = __builtin_amdgcn_mfma_f32_16x16x32_bf16(kf2, qf[qt][2], sx[qt][kt16], 0, 0, 0);
      }
    }
    __builtin_amdgcn_s_setprio(0);

    bf16x8 pf[2][4];
#pragma unroll
    for (int qt = 0; qt < 2; qt++) {
      float mx = -1e30f;
#pragma unroll
      for (int t = 0; t < 8; t++)
#pragma unroll
        for (int r = 0; r < 4; r++) mx = fmaxf(mx, sx[qt][t][r]);
      mx = fmaxf(mx, __shfl_xor(mx, 16));
      mx = fmaxf(mx, __shfl_xor(mx, 32));
      float mxs = mx * kscale;
      if (!__all(mxs <= mo[qt] + 8.f)) {
        float mnew = fmaxf(mo[qt], mxs);
        float alpha = fexp2(mo[qt] - mnew);
        mo[qt] = mnew;
        lsum[qt] *= alpha;
#pragma unroll
        for (int dt = 0; dt < 5; dt++) acc[qt][dt] *= alpha;
      }
      float ls = 0.f;
#pragma unroll
      for (int t = 0; t < 8; t++)
#pragma unroll
        for (int r = 0; r < 4; r++) {
          float p = fexp2(fmaf(sx[qt][t][r], kscale, -mo[qt]));
          sx[qt][t][r] = p;
          ls += p;
        }
      ls += __shfl_xor(ls, 16);
      ls += __shfl_xor(ls, 32);
      lsum[qt] += ls;
      char* pw = ldsP + wv * 4352;
#pragma unroll
      for (int t = 0; t < 8; t++) {
        uint2 o;
        o.x = f2b2(sx[qt][t][0], sx[qt][t][1]);
        o.y = f2b2(sx[qt][t][2], sx[qt][t][3]);
        *(uint2*)(pw + lr * 272 + t * 32 + lq * 8) = o;
      }
#pragma unroll
      for (int ks = 0; ks < 4; ks++)
        pf[qt][ks] = *(const bf16x8*)(pw + lr * 272 + ks * 64 + lq * 16);
    }

    __builtin_amdgcn_s_setprio(1);
#pragma unroll
    for (int dt = 0; dt < 5; dt++)
#pragma unroll
      for (int ks = 0; ks < 4; ks++) {
        bf16x8 vf = *(const bf16x8*)(ldsV + (dt * 4 + ks) * 1024 + lane * 16);
#pragma unroll
        for (int qt = 0; qt < 2; qt++)
          acc[qt][dt] = __builtin_amdgcn_mfma_f32_16x16x32_bf16(vf, pf[qt][ks], acc[qt][dt], 0, 0, 0);
      }
    __builtin_amdgcn_s_setprio(0);
    __syncthreads();
  }

#pragma unroll
  for (int qt = 0; qt < 2; qt++) {
    float rl = 1.f / lsum[qt];
    int s = q0 + qt * 16 + lr;
#pragma unroll
    for (int dt = 0; dt < 5; dt++) {
      uint2 o;
      o.x = f2b2(acc[qt][dt][0] * rl, acc[qt][dt][1] * rl);
      o.y = f2b2(acc[qt][dt][2] * rl, acc[qt][dt][3] * rl);
      size_t ob = (size_t)s * HIDN + h * HD + dt * 16 + lq * 4;
      *(uint2*)(Ob + ob) = o;
    }
  }
}

// ---------------- launch ----------------
extern "C" void kernel_launch(void* const* d_in, const int* in_sizes, int n_in,
                              void* d_out, int out_size, void* d_ws, size_t ws_size,
                              hipStream_t stream) {
  (void)in_sizes; (void)n_in; (void)out_size; (void)ws_size;
  const float* hidden = (const float*)d_in[0];
  const float* cosb   = (const float*)d_in[1];
  const float* sinb   = (const float*)d_in[2];
  const float* qkvk   = (const float*)d_in[3];
  const float* qkvb   = (const float*)d_in[4];
  const float* projk  = (const float*)d_in[5];
  const float* projb  = (const float*)d_in[6];
  // d_in[7] cu_seqlens: uniform windows, unused

  char* ws = (char*)d_ws;
  u16* Abf = (u16*)(ws + 0);          // 41,943,040 B ; reused as attn-out after gemm1
  u16* Wt  = (u16*)(ws + 41943040);   //  9,830,400 B
  u16* Pt  = (u16*)(ws + 51773440);   //  3,276,800 B
  u16* Qb  = (u16*)(ws + 55050240);   // 50,331,648 B
  u16* Kb  = (u16*)(ws + 105381888);  // 50,331,648 B
  u16* Vtb = (u16*)(ws + 155713536);  // 41,943,040 B -> total 197,656,576 B

  static int attr_done = 0;
  if (!attr_done) {
    (void)hipFuncSetAttribute((const void*)&k_gemm8<1>,
                              hipFuncAttributeMaxDynamicSharedMemorySize, 131072);
    (void)hipFuncSetAttribute((const void*)&k_gemm8<0>,
                              hipFuncAttributeMaxDynamicSharedMemorySize, 131072);
    (void)hipGetLastError();  // clear any sticky error from attribute calls
    attr_done = 1;
  }

  k_cvt<<<20480, 256, 0, stream>>>(hidden, Abf);
  k_trans<<<dim3(60, 20), 256, 0, stream>>>(qkvk, Wt, 1280, 3840);
  k_trans<<<dim3(20, 20), 256, 0, stream>>>(projk, Pt, 1280, 1280);
  // qkv: M=16384 N=3840 -> 64 x 15 tiles of 256x256 = 960 blocks
  k_gemm8<1><<<960, 512, 131072, stream>>>(Abf, Wt, qkvb, nullptr, Qb, Kb, Vtb, 3840, 15);
  // rope on Q and K, one launch
  k_rope2<<<20480, 256, 0, stream>>>(Qb, Kb, cosb, sinb);
  k_attn<<<2048, 256, 0, stream>>>(Qb, Kb, Vtb, Abf);
  // proj: M=16384 N=1280 -> 64 x 5 tiles of 256x256 = 320 blocks
  k_gemm8<0><<<320, 512, 131072, stream>>>(Abf, Pt, projb, (float*)d_out,
                                           nullptr, nullptr, nullptr, 1280, 5);
}

// Round 6
// 598.585 us; speedup vs baseline: 1.4944x; 1.0340x over previous
//
#include <hip/hip_runtime.h>
#include <stdint.h>

#define SEQ 16384
#define HIDN 1280
#define NHEADS 16
#define HD 80
#define HDP 96
#define NWIN 16
#define WINSZ 1024

typedef unsigned short u16;
typedef unsigned int u32;
typedef __bf16 bf16x8 __attribute__((ext_vector_type(8)));
typedef float f32x4 __attribute__((ext_vector_type(4)));

#define AS1 __attribute__((address_space(1)))
#define AS3 __attribute__((address_space(3)))

// native cast -> v_cvt_pk_bf16_f32 (RNE)
__device__ __forceinline__ u16 f2b(float f) {
  __bf16 h = (__bf16)f;
  return __builtin_bit_cast(u16, h);
}
__device__ __forceinline__ u32 f2b2(float lo, float hi) {
  __bf16 l = (__bf16)lo, h = (__bf16)hi;
  return (u32)__builtin_bit_cast(u16, l) | ((u32)__builtin_bit_cast(u16, h) << 16);
}
__device__ __forceinline__ float b2f(u16 u) { return __uint_as_float(((u32)u) << 16); }

__device__ __forceinline__ float fexp2(float x) {
#if __has_builtin(__builtin_amdgcn_exp2f)
  return __builtin_amdgcn_exp2f(x);
#else
  return exp2f(x);
#endif
}

__device__ __forceinline__ void load_lds16(const void* g, void* l) {
  __builtin_amdgcn_global_load_lds((AS1 void*)g, (AS3 void*)l, 16, 0, 0);
}

// ---------------- fp32 -> bf16 flat convert ----------------
__global__ void k_cvt(const float* __restrict__ in, u16* __restrict__ out) {
  size_t i = ((size_t)blockIdx.x * 256 + threadIdx.x) * 4;
  float4 v = *(const float4*)(in + i);
  uint2 o;
  o.x = f2b2(v.x, v.y);
  o.y = f2b2(v.z, v.w);
  *(uint2*)(out + i) = o;
}

// ---------------- transpose f32 [R][C] -> bf16 [C][R] ----------------
__global__ void k_trans(const float* __restrict__ in, u16* __restrict__ out, int R, int C) {
  __shared__ float tile[64][65];
  int c0 = blockIdx.x * 64, r0 = blockIdx.y * 64;
  int tc = threadIdx.x & 63, tr4 = threadIdx.x >> 6;
#pragma unroll
  for (int i = 0; i < 16; i++) {
    int r = tr4 + i * 4;
    tile[r][tc] = in[(size_t)(r0 + r) * C + c0 + tc];
  }
  __syncthreads();
#pragma unroll
  for (int i = 0; i < 16; i++) {
    int r = tr4 + i * 4;
    out[(size_t)(c0 + r) * R + r0 + tc] = f2b(tile[tc][r]);
  }
}

// ---------------- deep-pipe GEMM: C[M,N] = A[M,K](bf16) * B^T[N,K](bf16) + bias ----------------
// 256x256 tile, 512 thr = 8 waves (2M x 4N), per-wave C = 128x64 = acc[8][4] (AGPR).
// BK=32, FOUR LDS buffers (4 x 32KB = 128KB), stage tile t+3 during tile t,
// counted vmcnt(8) at tile end. XOR swizzle W ^= ((line&7)<<4) (0 conflicts, measured).
// R6: ONE barrier per K-tile (was 4). R3/R5 both measured MfmaUtil=34% because the
// per-phase lockstep {all waves ds_read -> barrier -> all waves MFMA} serializes the
// LDS pipe (~1150 cyc/tile/CU) with the matrix pipe (~1240 cyc/tile/CU). Removing
// mid-tile barriers lets waves slip within the tile region so one wave's ds_reads
// overlap another's MFMAs (2 waves/SIMD), at zero register cost (R4 lesson: the
// unified file is at 128 VGPR + 128 AGPR = 256/wave cap -> no register prefetch).
// Safety with 1 barrier/tile: reads of buf(t&3) guarded by prior tile's vmcnt(8)+
// barrier; stage into buf((t+3)&3)=((t-1)&3) is issued after the tile(t-1) barrier,
// by which point every wave's reads of it completed (own lgkmcnt < own MFMA < barrier).
// MODE 0: proj -> f32 out.  MODE 1: qkv -> scatter Q/K [H][S][96], V -> Vt [H][80][S]

#define GBAR() asm volatile("s_barrier" ::: "memory")

template <int MODE>
__launch_bounds__(512, 2)
__global__ void k_gemm8(const u16* __restrict__ A, const u16* __restrict__ B,
                        const float* __restrict__ bias, float* __restrict__ outf,
                        u16* __restrict__ Qb, u16* __restrict__ Kb, u16* __restrict__ Vt,
                        int N, int ncol) {
  extern __shared__ char lds[];
  const int K = 1280;
  const int NT = 40;  // K / 32
  const int tid = threadIdx.x;
  const int wv = tid >> 6, lane = tid & 63;
  const int lr = lane & 15, lq = lane >> 4;
  const int wm = wv >> 2, wn = wv & 3;  // wm 0..1, wn 0..3
  const int id = blockIdx.x;
  const int xs = id & 7, rest = id >> 3;
  const int cb = rest % ncol, rs = rest / ncol;
  const int row0 = (rs * 8 + xs) * 256, col0 = cb * 256;

  // --- staging precompute: 2 slices of 1KB per wave per matrix per tile ---
  const u16* gA[2];
  const u16* gB[2];
  int Pst[2];
#pragma unroll
  for (int ld = 0; ld < 2; ld++) {
    int P = wv * 2048 + ld * 1024 + lane * 16;  // linear LDS byte within 16KB region
    int j = P >> 7;                              // 128B line
    int Wl = (P & 127) ^ ((j & 7) << 4);         // inverse swizzle -> logical
    int r = 2 * j + (Wl >> 6);                   // logical row 0..255
    int c = (Wl & 63) >> 1;                      // logical col 0..31 (elements)
    gA[ld] = A + (size_t)(row0 + r) * K + c;
    gB[ld] = B + (size_t)(col0 + r) * K + c;
    Pst[ld] = P;
  }

  // --- frag read offsets (physical, swizzled) ---
  int offA[2][4], offB[4];
#pragma unroll
  for (int ch = 0; ch < 2; ch++)
#pragma unroll
    for (int a = 0; a < 4; a++) {
      int r = wm * 128 + ch * 64 + a * 16 + lr;
      int j = r >> 1;
      int Wl = ((r & 1) << 6) | (lq << 4);
      offA[ch][a] = j * 128 + (Wl ^ ((j & 7) << 4));
    }
#pragma unroll
  for (int ni = 0; ni < 4; ni++) {
    int r = wn * 64 + ni * 16 + lr;
    int j = r >> 1;
    int Wl = ((r & 1) << 6) | (lq << 4);
    offB[ni] = 16384 + j * 128 + (Wl ^ ((j & 7) << 4));
  }

  f32x4 acc[8][4];
#pragma unroll
  for (int i = 0; i < 8; i++)
#pragma unroll
    for (int j = 0; j < 4; j++) acc[i][j] = (f32x4){0.f, 0.f, 0.f, 0.f};

// stage one matrix tile (mat: 0=A 1=B) of K-tile kt -> LDS buf (kt&3)
#define STAGE(mat_, kt_)                                             \
  do {                                                               \
    char* lb_ = lds + (((kt_) & 3) << 15) + ((mat_) << 14);          \
    const u16* g0_ = (mat_) ? gB[0] : gA[0];                         \
    const u16* g1_ = (mat_) ? gB[1] : gA[1];                         \
    int ko_ = (kt_) * 32;                                            \
    load_lds16(g0_ + ko_, lb_ + Pst[0]);                             \
    load_lds16(g1_ + ko_, lb_ + Pst[1]);                             \
  } while (0)

#define MFMA16(dst_, af_, bf_)                                               \
  do {                                                                       \
    __builtin_amdgcn_s_setprio(1);                                           \
    _Pragma("unroll") for (int a_ = 0; a_ < 4; a_++)                         \
        _Pragma("unroll") for (int n_ = 0; n_ < 4; n_++)                     \
            acc[dst_ + a_][n_] = __builtin_amdgcn_mfma_f32_16x16x32_bf16(    \
                af_[a_], bf_[n_], acc[dst_ + a_][n_], 0, 0, 0);              \
    __builtin_amdgcn_s_setprio(0);                                           \
  } while (0)

  // --- prologue: stage tiles 0,1,2 (12 loads/thread) ---
  STAGE(0, 0);
  STAGE(1, 0);
  STAGE(0, 1);
  STAGE(1, 1);
  STAGE(0, 2);
  STAGE(1, 2);
  asm volatile("s_waitcnt vmcnt(8)" ::: "memory");  // tile0 fully landed
  GBAR();

#pragma unroll 4
  for (int t = 0; t < NT; t++) {
    const int bb = (t & 3) << 15;
    bf16x8 bfr[4], af0[4], af1[4];

    // reads for M-half 0; stage A of t+3
#pragma unroll
    for (int ni = 0; ni < 4; ni++) bfr[ni] = *(const bf16x8*)(lds + bb + offB[ni]);
#pragma unroll
    for (int a = 0; a < 4; a++) af0[a] = *(const bf16x8*)(lds + bb + offA[0][a]);
    if (t + 3 < NT) STAGE(0, t + 3);
    MFMA16(0, af0, bfr);

    // reads for M-half 1; stage B of t+3
#pragma unroll
    for (int a = 0; a < 4; a++) af1[a] = *(const bf16x8*)(lds + bb + offA[1][a]);
    if (t + 3 < NT) STAGE(1, t + 3);
    MFMA16(4, af1, bfr);

    // tile-boundary: tile t+1 fully landed, then one barrier
    if (t + 3 < NT)
      asm volatile("s_waitcnt vmcnt(8)" ::: "memory");
    else if (t == NT - 3)
      asm volatile("s_waitcnt vmcnt(4)" ::: "memory");
    else if (t == NT - 2)
      asm volatile("s_waitcnt vmcnt(0)" ::: "memory");
    GBAR();
  }
#undef STAGE
#undef MFMA16

  // --- epilogue: C/D layout col=lane&15, row=(lane>>4)*4+reg ---
#pragma unroll
  for (int ni = 0; ni < 4; ni++) {
    int col = col0 + wn * 64 + ni * 16 + lr;
    float bs = bias[col];
    if (MODE == 0) {
#pragma unroll
      for (int mi = 0; mi < 8; mi++)
#pragma unroll
        for (int r = 0; r < 4; r++) {
          int row = row0 + wm * 128 + mi * 16 + lq * 4 + r;
          outf[(size_t)row * N + col] = acc[mi][ni][r] + bs;
        }
    } else {
      int seg = col / HIDN;  // 0=q 1=k 2=v (uniform per 16-col tile)
      int cl = col - seg * HIDN;
      int h = cl / HD, d = cl - h * HD;
      if (seg == 2) {
#pragma unroll
        for (int mi = 0; mi < 8; mi++) {
          int row = row0 + wm * 128 + mi * 16 + lq * 4;
          uint2 o;
          o.x = f2b2(acc[mi][ni][0] + bs, acc[mi][ni][1] + bs);
          o.y = f2b2(acc[mi][ni][2] + bs, acc[mi][ni][3] + bs);
          *(uint2*)(Vt + ((size_t)h * HD + d) * SEQ + row) = o;
        }
      } else {
        u16* Dst = (seg == 0) ? Qb : Kb;
#pragma unroll
        for (int mi = 0; mi < 8; mi++)
#pragma unroll
          for (int r = 0; r < 4; r++) {
            int row = row0 + wm * 128 + mi * 16 + lq * 4 + r;
            Dst[((size_t)h * SEQ + row) * HDP + d] = f2b(acc[mi][ni][r] + bs);
          }
      }
    }
  }
}

// ---------------- in-place RoPE on Q and K [H][S][96] bf16, zero pad ----------------
__global__ void k_rope2(u16* __restrict__ Q, u16* __restrict__ K,
                        const float* __restrict__ cs, const float* __restrict__ sn) {
  int idx = blockIdx.x * 256 + threadIdx.x;  // [0, 2*16*16384*10)
  const int TOT = NHEADS * SEQ * 10;
  u16* X = Q;
  if (idx >= TOT) { X = K; idx -= TOT; }
  int h = idx / (SEQ * 10);
  int rem = idx - h * (SEQ * 10);
  int s = rem / 10;
  int t = rem - s * 10;
  int d = t * 4;
  size_t base = ((size_t)h * SEQ + s) * HDP;
  float4 cv = *(const float4*)(cs + s * HD + d);
  float4 sv = *(const float4*)(sn + s * HD + d);
  uint2 a = *(const uint2*)(X + base + d);
  uint2 b = *(const uint2*)(X + base + d + 40);
  float x1[4], x2[4];
  x1[0] = b2f(a.x & 0xffffu); x1[1] = b2f(a.x >> 16);
  x1[2] = b2f(a.y & 0xffffu); x1[3] = b2f(a.y >> 16);
  x2[0] = b2f(b.x & 0xffffu); x2[1] = b2f(b.x >> 16);
  x2[2] = b2f(b.y & 0xffffu); x2[3] = b2f(b.y >> 16);
  uint2 o1, o2;
  o1.x = f2b2(x1[0] * cv.x - x2[0] * sv.x, x1[1] * cv.y - x2[1] * sv.y);
  o1.y = f2b2(x1[2] * cv.z - x2[2] * sv.z, x1[3] * cv.w - x2[3] * sv.w);
  o2.x = f2b2(x2[0] * cv.x + x1[0] * sv.x, x2[1] * cv.y + x1[1] * sv.y);
  o2.y = f2b2(x2[2] * cv.z + x1[2] * sv.z, x2[3] * cv.w + x1[3] * sv.w);
  *(uint2*)(X + base + d) = o1;
  *(uint2*)(X + base + d + 40) = o2;
  if (t < 4) {
    uint2 z; z.x = 0; z.y = 0;
    *(uint2*)(X + base + 80 + t * 4) = z;
  }
}

// ---------------- windowed flash attention ----------------
__launch_bounds__(256, 2)
__global__ void k_attn(const u16* __restrict__ Qb, const u16* __restrict__ Kb,
                       const u16* __restrict__ Vt, u16* __restrict__ Ob) {
  __shared__ char lds[24576 + 20480 + 4 * 4352];
  char* ldsK = lds;
  char* ldsV = lds + 24576;
  char* ldsP = lds + 45056;

  const int tid = threadIdx.x;
  const int wv = tid >> 6, lane = tid & 63;
  const int lr = lane & 15, lq = lane >> 4;

  const int b = blockIdx.x;
  const int qblk = b & 7, h = (b >> 3) & 15, w = b >> 7;
  const int q0 = w * WINSZ + qblk * 128 + wv * 32;
  const int kwin = w * WINSZ;

  bf16x8 qf[2][3];
#pragma unroll
  for (int qt = 0; qt < 2; qt++)
#pragma unroll
    for (int ds = 0; ds < 3; ds++)
      qf[qt][ds] = *(const bf16x8*)(Qb + ((size_t)h * SEQ + q0 + qt * 16 + lr) * HDP + ds * 32 + lq * 8);

  f32x4 acc[2][5];
#pragma unroll
  for (int i = 0; i < 2; i++)
#pragma unroll
    for (int j = 0; j < 5; j++) acc[i][j] = (f32x4){0.f, 0.f, 0.f, 0.f};
  float mo[2] = {-1e30f, -1e30f};
  float lsum[2] = {0.f, 0.f};
  const float kscale = 0.11180339887498949f * 1.4426950408889634f;  // 1/sqrt(80) * log2(e)

  for (int kt = 0; kt < 8; kt++) {
    int k0 = kwin + kt * 128;
#pragma unroll
    for (int li = 0; li < 11; li++) {
      int g = li * 4 + wv;
      const u16* gp;
      char* lp;
      if (g < 24) {
        int kt16 = g / 3, ds = g - kt16 * 3;
        gp = Kb + ((size_t)h * SEQ + k0 + kt16 * 16 + lr) * HDP + ds * 32 + lq * 8;
        lp = ldsK + g * 1024;
      } else {
        int g2 = g - 24;
        int dt = g2 >> 2, ks = g2 & 3;
        gp = Vt + ((size_t)h * HD + dt * 16 + lr) * SEQ + k0 + ks * 32 + lq * 8;
        lp = ldsV + g2 * 1024;
      }
      load_lds16(gp, lp);
    }
    __syncthreads();

    f32x4 sx[2][8];
#pragma unroll
    for (int i = 0; i < 2; i++)
#pragma unroll
      for (int j = 0; j < 8; j++) sx[i][j] = (f32x4){0.f, 0.f, 0.f, 0.f};
    __builtin_amdgcn_s_setprio(1);
#pragma unroll
    for (int kt16 = 0; kt16 < 8; kt16++) {
      bf16x8 kf0 = *(const bf16x8*)(ldsK + (kt16 * 3 + 0) * 1024 + lane * 16);
      bf16x8 kf1 = *(const bf16x8*)(ldsK + (kt16 * 3 + 1) * 1024 + lane * 16);
      bf16x8 kf2 = *(const bf16x8*)(ldsK + (kt16 * 3 + 2) * 1024 + lane * 16);
#pragma unroll
      for (int qt = 0; qt < 2; qt++) {
        sx[qt][kt16] = __builtin_amdgcn_mfma_f32_16x16x32_bf16(kf0, qf[qt][0], sx[qt][kt16], 0, 0, 0);
        sx[qt][kt16] = __builtin_amdgcn_mfma_f32_16x16x32_bf16(kf1, qf[qt][1], sx[qt][kt16], 0, 0, 0);
        sx[qt][kt16] = __builtin_amdgcn_mfma_f32_16x16x32_bf16(kf2, qf[qt][2], sx[qt][kt16], 0, 0, 0);
      }
    }
    __builtin_amdgcn_s_setprio(0);

    bf16x8 pf[2][4];
#pragma unroll
    for (int qt = 0; qt < 2; qt++) {
      float mx = -1e30f;
#pragma unroll
      for (int t = 0; t < 8; t++)
#pragma unroll
        for (int r = 0; r < 4; r++) mx = fmaxf(mx, sx[qt][t][r]);
      mx = fmaxf(mx, __shfl_xor(mx, 16));
      mx = fmaxf(mx, __shfl_xor(mx, 32));
      float mxs = mx * kscale;
      if (!__all(mxs <= mo[qt] + 8.f)) {
        float mnew = fmaxf(mo[qt], mxs);
        float alpha = fexp2(mo[qt] - mnew);
        mo[qt] = mnew;
        lsum[qt] *= alpha;
#pragma unroll
        for (int dt = 0; dt < 5; dt++) acc[qt][dt] *= alpha;
      }
      float ls = 0.f;
#pragma unroll
      for (int t = 0; t < 8; t++)
#pragma unroll
        for (int r = 0; r < 4; r++) {
          float p = fexp2(fmaf(sx[qt][t][r], kscale, -mo[qt]));
          sx[qt][t][r] = p;
          ls += p;
        }
      ls += __shfl_xor(ls, 16);
      ls += __shfl_xor(ls, 32);
      lsum[qt] += ls;
      char* pw = ldsP + wv * 4352;
#pragma unroll
      for (int t = 0; t < 8; t++) {
        uint2 o;
        o.x = f2b2(sx[qt][t][0], sx[qt][t][1]);
        o.y = f2b2(sx[qt][t][2], sx[qt][t][3]);
        *(uint2*)(pw + lr * 272 + t * 32 + lq * 8) = o;
      }
#pragma unroll
      for (int ks = 0; ks < 4; ks++)
        pf[qt][ks] = *(const bf16x8*)(pw + lr * 272 + ks * 64 + lq * 16);
    }

    __builtin_amdgcn_s_setprio(1);
#pragma unroll
    for (int dt = 0; dt < 5; dt++)
#pragma unroll
      for (int ks = 0; ks < 4; ks++) {
        bf16x8 vf = *(const bf16x8*)(ldsV + (dt * 4 + ks) * 1024 + lane * 16);
#pragma unroll
        for (int qt = 0; qt < 2; qt++)
          acc[qt][dt] = __builtin_amdgcn_mfma_f32_16x16x32_bf16(vf, pf[qt][ks], acc[qt][dt], 0, 0, 0);
      }
    __builtin_amdgcn_s_setprio(0);
    __syncthreads();
  }

#pragma unroll
  for (int qt = 0; qt < 2; qt++) {
    float rl = 1.f / lsum[qt];
    int s = q0 + qt * 16 + lr;
#pragma unroll
    for (int dt = 0; dt < 5; dt++) {
      uint2 o;
      o.x = f2b2(acc[qt][dt][0] * rl, acc[qt][dt][1] * rl);
      o.y = f2b2(acc[qt][dt][2] * rl, acc[qt][dt][3] * rl);
      size_t ob = (size_t)s * HIDN + h * HD + dt * 16 + lq * 4;
      *(uint2*)(Ob + ob) = o;
    }
  }
}

// ---------------- launch ----------------
extern "C" void kernel_launch(void* const* d_in, const int* in_sizes, int n_in,
                              void* d_out, int out_size, void* d_ws, size_t ws_size,
                              hipStream_t stream) {
  (void)in_sizes; (void)n_in; (void)out_size; (void)ws_size;
  const float* hidden = (const float*)d_in[0];
  const float* cosb   = (const float*)d_in[1];
  const float* sinb   = (const float*)d_in[2];
  const float* qkvk   = (const float*)d_in[3];
  const float* qkvb   = (const float*)d_in[4];
  const float* projk  = (const float*)d_in[5];
  const float* projb  = (const float*)d_in[6];
  // d_in[7] cu_seqlens: uniform windows, unused

  char* ws = (char*)d_ws;
  u16* Abf = (u16*)(ws + 0);          // 41,943,040 B ; reused as attn-out after gemm1
  u16* Wt  = (u16*)(ws + 41943040);   //  9,830,400 B
  u16* Pt  = (u16*)(ws + 51773440);   //  3,276,800 B
  u16* Qb  = (u16*)(ws + 55050240);   // 50,331,648 B
  u16* Kb  = (u16*)(ws + 105381888);  // 50,331,648 B
  u16* Vtb = (u16*)(ws + 155713536);  // 41,943,040 B -> total 197,656,576 B

  static int attr_done = 0;
  if (!attr_done) {
    (void)hipFuncSetAttribute((const void*)&k_gemm8<1>,
                              hipFuncAttributeMaxDynamicSharedMemorySize, 131072);
    (void)hipFuncSetAttribute((const void*)&k_gemm8<0>,
                              hipFuncAttributeMaxDynamicSharedMemorySize, 131072);
    (void)hipGetLastError();  // clear any sticky error from attribute calls
    attr_done = 1;
  }

  k_cvt<<<20480, 256, 0, stream>>>(hidden, Abf);
  k_trans<<<dim3(60, 20), 256, 0, stream>>>(qkvk, Wt, 1280, 3840);
  k_trans<<<dim3(20, 20), 256, 0, stream>>>(projk, Pt, 1280, 1280);
  // qkv: M=16384 N=3840 -> 64 x 15 tiles of 256x256 = 960 blocks
  k_gemm8<1><<<960, 512, 131072, stream>>>(Abf, Wt, qkvb, nullptr, Qb, Kb, Vtb, 3840, 15);
  // rope on Q and K, one launch
  k_rope2<<<20480, 256, 0, stream>>>(Qb, Kb, cosb, sinb);
  k_attn<<<2048, 256, 0, stream>>>(Qb, Kb, Vtb, Abf);
  // proj: M=16384 N=1280 -> 64 x 5 tiles of 256x256 = 320 blocks
  k_gemm8<0><<<320, 512, 131072, stream>>>(Abf, Pt, projb, (float*)d_out,
                                           nullptr, nullptr, nullptr, 1280, 5);
}